// Round 16
// baseline (815.053 us; speedup 1.0000x reference)
//
#include <hip/hip_runtime.h>
#include <hip/hip_bf16.h>
#include <stdint.h>
#include <stdio.h>

// Problem geometry (fixed by the reference)
#define M_DIM 8192    // 4*2048
#define K_DIM 4096    // IN_FEATURES
#define N_DIM 11008   // OUT_FEATURES

#define BM 256
#define BN 256
#define BK 64
#define NT (K_DIM / BK)           // 64 K-tiles
#define TILES_M (M_DIM / BM)      // 32
#define TILES_N (N_DIM / BN)      // 43
#define NWG (TILES_M * TILES_N)   // 1376

typedef __bf16 bf16x8 __attribute__((ext_vector_type(8)));
typedef float f32x16 __attribute__((ext_vector_type(16)));

__device__ __constant__ float kFp4Code[16] = {
    0.0f,           0.0052083333f,  0.6666666666f, 1.0f,
    0.3333333333f,  0.5f,           0.1666666666f, 0.25f,
    -0.0f,          -0.0052083333f, -0.6666666666f, -1.0f,
    -0.3333333333f, -0.5f,          -0.1666666666f, -0.25f
};

// ---------------------------------------------------------------------------
// Kernel 1: FP4 dequant -> bf16 W [N_DIM][K_DIM]
// ---------------------------------------------------------------------------
__global__ __launch_bounds__(256) void fp4_dequant_kernel(
    const int* __restrict__ codes, const float* __restrict__ absmax,
    __hip_bfloat16* __restrict__ w)
{
    __shared__ float lut[16];
    if (threadIdx.x < 16) lut[threadIdx.x] = kFp4Code[threadIdx.x];
    __syncthreads();

    const int t = blockIdx.x * 256 + threadIdx.x;  // < 5,636,096
    const int4* cp = (const int4*)codes;
    const int4 c0 = cp[2 * t];
    const int4 c1 = cp[2 * t + 1];
    const float am = absmax[t >> 3];

    union { int4 v; __hip_bfloat16 h[8]; } u;
    u.h[0] = __float2bfloat16(lut[c0.x & 15] * am);
    u.h[1] = __float2bfloat16(lut[c0.y & 15] * am);
    u.h[2] = __float2bfloat16(lut[c0.z & 15] * am);
    u.h[3] = __float2bfloat16(lut[c0.w & 15] * am);
    u.h[4] = __float2bfloat16(lut[c1.x & 15] * am);
    u.h[5] = __float2bfloat16(lut[c1.y & 15] * am);
    u.h[6] = __float2bfloat16(lut[c1.z & 15] * am);
    u.h[7] = __float2bfloat16(lut[c1.w & 15] * am);
    ((int4*)w)[t] = u.v;
}

// ---------------------------------------------------------------------------
// Kernel 2: x fp32 -> bf16  [M_DIM][K_DIM]
// ---------------------------------------------------------------------------
__global__ __launch_bounds__(256) void f32_to_bf16_kernel(
    const float* __restrict__ x, __hip_bfloat16* __restrict__ y)
{
    const int t = blockIdx.x * 256 + threadIdx.x;  // < 4,194,304
    const float4* xp = (const float4*)x;
    const float4 a = xp[2 * t];
    const float4 b = xp[2 * t + 1];
    union { int4 v; __hip_bfloat16 h[8]; } u;
    u.h[0] = __float2bfloat16(a.x);
    u.h[1] = __float2bfloat16(a.y);
    u.h[2] = __float2bfloat16(a.z);
    u.h[3] = __float2bfloat16(a.w);
    u.h[4] = __float2bfloat16(b.x);
    u.h[5] = __float2bfloat16(b.y);
    u.h[6] = __float2bfloat16(b.z);
    u.h[7] = __float2bfloat16(b.w);
    ((int4*)y)[t] = u.v;
}

// ---------------------------------------------------------------------------
// Kernel 3: bf16 GEMM, C = A * B^T + bias  (256x256, 2 windows/K-tile,
//                                           32x32x16 MFMA)
//
// Round-15 change vs round-11: 16x16x32 -> 32x32x16 MFMA. Corrected cycle
// model (m06 ceiling: 844 FLOP/cyc/SIMD -> 19.4 cyc per 16x16x32): r11's
// window = 2500 cyc vs MFMA floor 1242 -> MfmaUtil 48-50% EXACTLY as
// measured. 32x32x16 runs at 968 FLOP/cyc/SIMD (m119: 2382 TF) -> floor
// 2166 cyc/tile (-13%), and HALVES the MFMA instruction count (32 vs 64
// per wave-tile) -> if the unexplained 465 cyc/window VALU (18.6% busy,
// ~20 visible instrs) is per-MFMA compiler glue, it halves too.
//
// Fragment mapping (32x32x16 bf16):
//  A/B operand: row/col = lane&31, k = (lane>>5)*8 + j  (8 contiguous bf16);
//  C/D (m74/m101-verified): col = lane&31,
//      row = (reg&3) + 8*(reg>>2) + 4*(lane>>5), reg in [0,16).
//  LDS read addr: row*128 + ((ks*2 + (lane>>5)) ^ (row&7))*16; row&7 ==
//  lane&7 (all row bases are multiples of 32). XOR doesn't fold additively
//  across ks -> 4 precomputed pointers per operand (pAk[4], pBk[4]); mpos
//  (+4096), hi-half (+16384), buffer (+65536) are compile-time offsets.
//  Read pattern is LDS-throughput-floor-bound (8 lanes per 4-bank group x
//  16B = the 1KB/wave minimum) -- conflict counter may tick, time floor-bound.
//
// Window/stage/vmcnt/barrier skeleton: BYTE-IDENTICAL to round 11
// (ledger re-audited: same confirm + overwrite guarantees).
// 2D brick order (round-9 win). LDS 128KB: 2 dbuf x {Alo,Ahi,Blo,Bhi}.
// ---------------------------------------------------------------------------
#define STAGE(gbase, eoff, loff)                                              \
    __builtin_amdgcn_global_load_lds(                                         \
        (const __attribute__((address_space(1))) void*)((gbase) + (eoff)),    \
        (__attribute__((address_space(3))) void*)(lds + (loff)), 16, 0, 0)

// 8 MFMAs of 32x32x16: one quadrant (2 mpos x 4 ks), ks-outer (2 chains)
__device__ __forceinline__ void mfma_quad32(
    f32x16 (&accq)[2], bf16x8 (&av)[2][4], bf16x8 (&bv)[4])
{
#pragma unroll
    for (int ks = 0; ks < 4; ++ks)
#pragma unroll
        for (int mp = 0; mp < 2; ++mp)
            accq[mp] = __builtin_amdgcn_mfma_f32_32x32x16_bf16(
                av[mp][ks], bv[ks], accq[mp], 0, 0, 0);
}

template<int BUF>
__device__ __forceinline__ void tile_body(
    int t, f32x16 (&acc)[4][2],
    const __hip_bfloat16* __restrict__ A, const __hip_bfloat16* __restrict__ B,
    char* lds,
    const int (&sA_lo)[2], const int (&sA_hi)[2],
    const int (&sB_lo)[2], const int (&sB_hi)[2],
    int dst0, int dst1,
    const char* const (&pAk)[4], const char* const (&pBk)[4])
{
    constexpr int LB  = BUF * 65536;         // this tile's buffer
    constexpr int LB1 = (BUF ^ 1) * 65536;   // (t+1)'s buffer
    const int koff1 = ((t + 1) & (NT - 1)) * 64;
    const int koff2 = ((t + 2) & (NT - 1)) * 64;

    bf16x8 avLo[2][4], avHi[2][4], bvLo[4], bvHi[4];

    // ================= W0 =================
    STAGE(A, sA_hi[0] + koff1, LB1 + 16384 + dst0);
    STAGE(A, sA_hi[1] + koff1, LB1 + 16384 + dst1);
    STAGE(B, sB_hi[0] + koff1, LB1 + 49152 + dst0);
    STAGE(B, sB_hi[1] + koff1, LB1 + 49152 + dst1);
    // pre-bar reads (confirmed at W1(t-1) vmcnt+bar): avLo(t), bvLo(t)
#pragma unroll
    for (int mp = 0; mp < 2; ++mp)
#pragma unroll
        for (int ks = 0; ks < 4; ++ks)
            avLo[mp][ks] = *(const bf16x8*)(pAk[ks] + LB + mp * 4096);
#pragma unroll
    for (int ks = 0; ks < 4; ++ks)
        bvLo[ks] = *(const bf16x8*)(pBk[ks] + LB);
    asm volatile("s_waitcnt vmcnt(8)" ::: "memory");
    __builtin_amdgcn_s_barrier();
    __builtin_amdgcn_sched_barrier(0);     // nothing crosses bar#1
    __builtin_amdgcn_s_setprio(1);
    mfma_quad32(acc[0], avLo, bvLo);       // Q(0,0)
    // mid-cluster read: bvHi(t) all-wave-safe only after bar#1(W0(t))
#pragma unroll
    for (int ks = 0; ks < 4; ++ks)
        bvHi[ks] = *(const bf16x8*)(pBk[ks] + LB + 16384);
    mfma_quad32(acc[1], avLo, bvHi);       // Q(0,1)
    __builtin_amdgcn_s_setprio(0);
    __builtin_amdgcn_s_barrier();

    // ================= W1 =================
    STAGE(A, sA_lo[0] + koff2, LB + dst0);
    STAGE(A, sA_lo[1] + koff2, LB + dst1);
    STAGE(B, sB_lo[0] + koff2, LB + 32768 + dst0);
    STAGE(B, sB_lo[1] + koff2, LB + 32768 + dst1);
    // pre-bar read avHi(t) (all-wave-confirmed at W0(t) bar#1)
#pragma unroll
    for (int mp = 0; mp < 2; ++mp)
#pragma unroll
        for (int ks = 0; ks < 4; ++ks)
            avHi[mp][ks] = *(const bf16x8*)(pAk[ks] + LB + 16384 + mp * 4096);
    asm volatile("s_waitcnt vmcnt(8)" ::: "memory");
    __builtin_amdgcn_s_barrier();
    __builtin_amdgcn_sched_barrier(0);
    __builtin_amdgcn_s_setprio(1);
    mfma_quad32(acc[2], avHi, bvHi);       // Q(1,1)
    mfma_quad32(acc[3], avHi, bvLo);       // Q(1,0)
    __builtin_amdgcn_s_setprio(0);
    __builtin_amdgcn_s_barrier();
}

__global__ __launch_bounds__(512, 2) void gemm_bf16_32x32(
    const __hip_bfloat16* __restrict__ A, const __hip_bfloat16* __restrict__ B,
    const float* __restrict__ bias, float* __restrict__ C)
{
    extern __shared__ char lds[];  // 131072 B

    const int tid = threadIdx.x;
    const int lane = tid & 63;
    const int wid = tid >> 6;       // 0..7
    const int wr = wid >> 2;        // 0..1 (M split)
    const int wc = wid & 3;         // 0..3 (N split)
    const int lane31 = lane & 31;
    const int h = lane >> 5;        // 0/1
    const int x3 = lane & 7;        // XOR key (row&7 == lane&7)

    // XCD stripe (bijective) + 2D brick order (round-9): per-XCD 8x4 bricks.
    const int wg = blockIdx.x;
    const int s = (wg & 7) * (NWG / 8) + (wg >> 3);
    int bm, bn;
    if (s < 1280) {                 // 10 groups of width 4 (8x4 bricks)
        const int g = s >> 7;
        const int j = s & 127;
        bm = j >> 2;
        bn = g * 4 + (j & 3);
    } else {                        // last group: width 3
        const int j = s - 1280;     // 0..95
        bm = j / 3;
        bn = 40 + j % 3;
    }
    const int m0 = bm * BM;
    const int n0 = bn * BN;

    // ---- Stage-source element offsets (per lane, once) ----
    int sA_lo[2], sA_hi[2], sB_lo[2], sB_hi[2];
#pragma unroll
    for (int c = 0; c < 2; ++c) {
        const int idx = c * 512 + tid;          // 0..1023 chunk id (linear LDS)
        const int row = idx >> 3;               // 0..127
        const int scol = (idx & 7) ^ (row & 7); // pre-swizzled source chunk
        sA_lo[c] = (m0 + row) * K_DIM + scol * 8;
        sA_hi[c] = sA_lo[c] + 128 * K_DIM;
        sB_lo[c] = (n0 + row) * K_DIM + scol * 8;
        sB_hi[c] = sB_lo[c] + 128 * K_DIM;
    }
    const int dst0 = wid * 1024;          // (c*512 + wid*64)*16, c=0
    const int dst1 = 8192 + wid * 1024;   // c=1

    // ---- Fragment-read base pointers, one per ks (buf0; +offsets imm) ----
    const char* pAk[4];
    const char* pBk[4];
#pragma unroll
    for (int ks = 0; ks < 4; ++ks) {
        pAk[ks] = lds + (wr * 64 + lane31) * 128 + (((ks * 2 + h) ^ x3) * 16);
        pBk[ks] = lds + 32768 + (wc * 32 + lane31) * 128 + (((ks * 2 + h) ^ x3) * 16);
    }

    // acc quadrants: 0=(0,0) 1=(0,1) 2=(1,1) 3=(1,0); [quadrant][mpos]
    f32x16 acc[4][2];
#pragma unroll
    for (int q = 0; q < 4; ++q)
#pragma unroll
        for (int mp = 0; mp < 2; ++mp)
#pragma unroll
            for (int r = 0; r < 16; ++r)
                acc[q][mp][r] = 0.f;

    // Prologue pair-stream (FIFO matches steady state):
    //  {Alo(0),Blo(0)} ; {Ahi(0),Bhi(0)} ; {Alo(1),Blo(1)}
    STAGE(A, sA_lo[0], dst0);                 STAGE(A, sA_lo[1], dst1);
    STAGE(B, sB_lo[0], 32768 + dst0);         STAGE(B, sB_lo[1], 32768 + dst1);
    STAGE(A, sA_hi[0], 16384 + dst0);         STAGE(A, sA_hi[1], 16384 + dst1);
    STAGE(B, sB_hi[0], 49152 + dst0);         STAGE(B, sB_hi[1], 49152 + dst1);
    STAGE(A, sA_lo[0] + 64, 65536 + dst0);    STAGE(A, sA_lo[1] + 64, 65536 + dst1);
    STAGE(B, sB_lo[0] + 64, 98304 + dst0);    STAGE(B, sB_lo[1] + 64, 98304 + dst1);
    asm volatile("s_waitcnt vmcnt(8)" ::: "memory"); // confirms {Alo,Blo}(0)
    __builtin_amdgcn_s_barrier();

    for (int t = 0; t < NT; t += 2) {
        tile_body<0>(t,     acc, A, B, lds, sA_lo, sA_hi, sB_lo, sB_hi,
                     dst0, dst1, pAk, pBk);
        tile_body<1>(t + 1, acc, A, B, lds, sA_lo, sA_hi, sB_lo, sB_hi,
                     dst0, dst1, pAk, pBk);
    }

    // Epilogue. 32x32 C/D layout: col = lane&31,
    //   row = (reg&3) + 8*(reg>>2) + 4*(lane>>5).
    // Nontemporal: C written once, never re-read -> don't churn L3.
#pragma unroll
    for (int q = 0; q < 4; ++q) {
        const int mqe = q >> 1;
        const int nqe = (q == 1 || q == 2) ? 1 : 0;
        const int col = n0 + nqe * 128 + wc * 32 + lane31;
        const float bval = bias[col];
#pragma unroll
        for (int mp = 0; mp < 2; ++mp) {
            const int rowbase = m0 + mqe * 128 + wr * 64 + mp * 32 + 4 * h;
#pragma unroll
            for (int r = 0; r < 16; ++r) {
                const int row = rowbase + (r & 3) + 8 * (r >> 2);
                __builtin_nontemporal_store(acc[q][mp][r] + bval,
                    &C[(size_t)row * N_DIM + col]);
            }
        }
    }
}

// ---------------------------------------------------------------------------
extern "C" void kernel_launch(void* const* d_in, const int* in_sizes, int n_in,
                              void* d_out, int out_size, void* d_ws, size_t ws_size,
                              hipStream_t stream)
{
    const float* x      = (const float*)d_in[0];  // [4,2048,4096] f32
    const int*   codes  = (const int*)d_in[1];    // [704512,64] i32
    const float* absmax = (const float*)d_in[2];  // [704512] f32
    const float* bias   = (const float*)d_in[3];  // [11008] f32
    float* out = (float*)d_out;                   // [4,2048,11008] f32

    const size_t w_bytes = (size_t)N_DIM * K_DIM * sizeof(__hip_bfloat16);
    const size_t x_bytes = (size_t)M_DIM * K_DIM * sizeof(__hip_bfloat16);
    if (ws_size < w_bytes + x_bytes) {
        fprintf(stderr, "kernel_launch: ws_size=%zu < needed %zu\n",
                ws_size, w_bytes + x_bytes);
        return;
    }
    __hip_bfloat16* wbf = (__hip_bfloat16*)d_ws;
    __hip_bfloat16* xbf = (__hip_bfloat16*)((char*)d_ws + w_bytes);

    hipFuncSetAttribute((const void*)gemm_bf16_32x32,
                        hipFuncAttributeMaxDynamicSharedMemorySize, 131072);

    fp4_dequant_kernel<<<dim3(22016), dim3(256), 0, stream>>>(codes, absmax, wbf);
    f32_to_bf16_kernel<<<dim3(16384), dim3(256), 0, stream>>>(x, xbf);
    gemm_bf16_32x32<<<dim3(NWG), dim3(512), 131072, stream>>>(xbf, wbf, bias, out);
}

// Round 17
// 728.398 us; speedup vs baseline: 1.1190x; 1.1190x over previous
//
#include <hip/hip_runtime.h>
#include <hip/hip_bf16.h>
#include <stdint.h>
#include <stdio.h>

// Problem geometry (fixed by the reference)
#define M_DIM 8192    // 4*2048
#define K_DIM 4096    // IN_FEATURES
#define N_DIM 11008   // OUT_FEATURES

#define BM 256
#define BN 256
#define BK 64
#define NT (K_DIM / BK)           // 64 K-tiles (power of 2 -> & wrap ok)
#define TILES_M (M_DIM / BM)      // 32
#define TILES_N (N_DIM / BN)      // 43
#define NWG (TILES_M * TILES_N)   // 1376

typedef __bf16 bf16x8 __attribute__((ext_vector_type(8)));
typedef float f32x4 __attribute__((ext_vector_type(4)));

__device__ __constant__ float kFp4Code[16] = {
    0.0f,           0.0052083333f,  0.6666666666f, 1.0f,
    0.3333333333f,  0.5f,           0.1666666666f, 0.25f,
    -0.0f,          -0.0052083333f, -0.6666666666f, -1.0f,
    -0.3333333333f, -0.5f,          -0.1666666666f, -0.25f
};

// ---------------------------------------------------------------------------
// Kernel 1 (fused prep): blocks [0, 22016): FP4 dequant -> bf16 W;
//                        blocks [22016, 38400): x fp32 -> bf16.
// Both are memory-bound streams; fusing saves one dispatch tail.
// ---------------------------------------------------------------------------
#define DEQ_BLOCKS 22016   // 45,088,768 / 8 / 256
#define CVT_BLOCKS 16384   // 33,554,432 / 8 / 256

__global__ __launch_bounds__(256) void prep_kernel(
    const int* __restrict__ codes, const float* __restrict__ absmax,
    const float* __restrict__ x,
    __hip_bfloat16* __restrict__ w, __hip_bfloat16* __restrict__ y)
{
    if (blockIdx.x < DEQ_BLOCKS) {
        __shared__ float lut[16];
        if (threadIdx.x < 16) lut[threadIdx.x] = kFp4Code[threadIdx.x];
        __syncthreads();

        const int t = blockIdx.x * 256 + threadIdx.x;  // < 5,636,096
        const int4* cp = (const int4*)codes;
        const int4 c0 = cp[2 * t];
        const int4 c1 = cp[2 * t + 1];
        const float am = absmax[t >> 3];

        union { int4 v; __hip_bfloat16 h[8]; } u;
        u.h[0] = __float2bfloat16(lut[c0.x & 15] * am);
        u.h[1] = __float2bfloat16(lut[c0.y & 15] * am);
        u.h[2] = __float2bfloat16(lut[c0.z & 15] * am);
        u.h[3] = __float2bfloat16(lut[c0.w & 15] * am);
        u.h[4] = __float2bfloat16(lut[c1.x & 15] * am);
        u.h[5] = __float2bfloat16(lut[c1.y & 15] * am);
        u.h[6] = __float2bfloat16(lut[c1.z & 15] * am);
        u.h[7] = __float2bfloat16(lut[c1.w & 15] * am);
        ((int4*)w)[t] = u.v;
    } else {
        const int t = (blockIdx.x - DEQ_BLOCKS) * 256 + threadIdx.x;  // < 4,194,304
        const float4* xp = (const float4*)x;
        const float4 a = xp[2 * t];
        const float4 b = xp[2 * t + 1];
        union { int4 v; __hip_bfloat16 h[8]; } u;
        u.h[0] = __float2bfloat16(a.x);
        u.h[1] = __float2bfloat16(a.y);
        u.h[2] = __float2bfloat16(a.z);
        u.h[3] = __float2bfloat16(a.w);
        u.h[4] = __float2bfloat16(b.x);
        u.h[5] = __float2bfloat16(b.y);
        u.h[6] = __float2bfloat16(b.z);
        u.h[7] = __float2bfloat16(b.w);
        ((int4*)y)[t] = u.v;
    }
}

// ---------------------------------------------------------------------------
// Kernel 2: bf16 GEMM, C = A * B^T + bias  (256x256 tile, TWO windows/K-tile)
// EXACT round-11 kernel (session best: 716 us GEMM, 0 conflicts, MfmaUtil 48%).
//
// Window structure (tile t, buf LB = (t&1)*64KB, LB1 = other):
//  W0: stage {A-hi,B-hi}(t+1)->LB1; read avLo,bvLo(t) [12 b128]; vmcnt(8);
//      bar; SCHED_BARRIER(0); MFMA Q00 x16; read bvHi(t) [4]; MFMA Q01 x16;
//      bar.
//  W1: stage {A-lo,B-lo}(t+2)->LB;  read avHi(t) [8];       vmcnt(8);
//      bar; SCHED_BARRIER(0); MFMA Q11 x16;                 MFMA Q10 x16;
//      bar.
// vmcnt ledger (pair-stream FIFO, 4 gloads/pair, 12 in flight at each wait):
//  vmcnt(8) at W0(t) confirms pair{Ahi,Bhi}(t); at W1(t) confirms
//  pair{Alo,Blo}(t+1). Cross-wave safety: avLo/bvLo(t) confirmed at W1(t-1)
//  vmcnt+bar; avHi(t) at W0(t) bar#1; bvHi(t) read MID-CLUSTER after
//  bar#1(W0(t)) with sched_barrier(0) preventing hoisting.
// Overwrite ledger: every region >=1 barrier between last consume and
//  overwriting stage issue (all cases audited round 11).
// 2D brick work order (round-9 win: FETCH 1.52->0.62 GB). XOR involution
// swizzle (round-2-proven, 0 conflicts). LDS 128KB: 2 dbuf x
// {A-lo@0, A-hi@16K, B-lo@32K, B-hi@48K}.
// Known floor of this structure (rounds 5-16): LDS-read min (2300 cyc/CU/tile,
// at the b128 minimum for 128x64 wave tiles) + MFMA floor (2483 cyc/SIMD)
// serialized; 7 overlap attacks null/negative.
// ---------------------------------------------------------------------------
#define STAGE(gbase, eoff, loff)                                              \
    __builtin_amdgcn_global_load_lds(                                         \
        (const __attribute__((address_space(1))) void*)((gbase) + (eoff)),    \
        (__attribute__((address_space(3))) void*)(lds + (loff)), 16, 0, 0)

// 16 MFMAs: one quadrant (4m x 2n x 2ks), ks-outer for dependence distance 8
__device__ __forceinline__ void mfma_half(
    f32x4 (&accq)[4][2], bf16x8 (&av)[4][2], bf16x8 (&bv)[2][2])
{
#pragma unroll
    for (int ks = 0; ks < 2; ++ks)
#pragma unroll
        for (int m = 0; m < 4; ++m)
#pragma unroll
            for (int n = 0; n < 2; ++n)
                accq[m][n] = __builtin_amdgcn_mfma_f32_16x16x32_bf16(
                    av[m][ks], bv[n][ks], accq[m][n], 0, 0, 0);
}

template<int BUF>
__device__ __forceinline__ void tile_body(
    int t, f32x4 (&acc)[4][4][2],
    const __hip_bfloat16* __restrict__ A, const __hip_bfloat16* __restrict__ B,
    char* lds,
    const int (&sA_lo)[2], const int (&sA_hi)[2],
    const int (&sB_lo)[2], const int (&sB_hi)[2],
    int dst0, int dst1,
    const char* pA0, const char* pA1, const char* pB0, const char* pB1)
{
    constexpr int LB  = BUF * 65536;         // this tile's buffer
    constexpr int LB1 = (BUF ^ 1) * 65536;   // (t+1)'s buffer
    const int koff1 = ((t + 1) & (NT - 1)) * 64;   // wave-uniform (SALU)
    const int koff2 = ((t + 2) & (NT - 1)) * 64;

    bf16x8 avLo[4][2], avHi[4][2], bvLo[2][2], bvHi[2][2];

    // ================= W0 =================
    STAGE(A, sA_hi[0] + koff1, LB1 + 16384 + dst0);
    STAGE(A, sA_hi[1] + koff1, LB1 + 16384 + dst1);
    STAGE(B, sB_hi[0] + koff1, LB1 + 49152 + dst0);
    STAGE(B, sB_hi[1] + koff1, LB1 + 49152 + dst1);
    // pre-bar reads (cross-wave-confirmed at W1(t-1) vmcnt+bar)
#pragma unroll
    for (int m = 0; m < 4; ++m) {
        avLo[m][0] = *(const bf16x8*)(pA0 + LB + m * 2048);
        avLo[m][1] = *(const bf16x8*)(pA1 + LB + m * 2048);
    }
#pragma unroll
    for (int n = 0; n < 2; ++n) {
        bvLo[n][0] = *(const bf16x8*)(pB0 + LB + n * 2048);
        bvLo[n][1] = *(const bf16x8*)(pB1 + LB + n * 2048);
    }
    asm volatile("s_waitcnt vmcnt(8)" ::: "memory");
    __builtin_amdgcn_s_barrier();
    __builtin_amdgcn_sched_barrier(0);     // nothing crosses bar#1
    __builtin_amdgcn_s_setprio(1);
    mfma_half(acc[0], avLo, bvLo);         // Q(0,0)
    // mid-cluster read: bvHi(t) is cross-wave-safe only after bar#1(W0(t))
#pragma unroll
    for (int n = 0; n < 2; ++n) {
        bvHi[n][0] = *(const bf16x8*)(pB0 + LB + 16384 + n * 2048);
        bvHi[n][1] = *(const bf16x8*)(pB1 + LB + 16384 + n * 2048);
    }
    mfma_half(acc[1], avLo, bvHi);         // Q(0,1)
    __builtin_amdgcn_s_setprio(0);
    __builtin_amdgcn_s_barrier();

    // ================= W1 =================
    STAGE(A, sA_lo[0] + koff2, LB + dst0);
    STAGE(A, sA_lo[1] + koff2, LB + dst1);
    STAGE(B, sB_lo[0] + koff2, LB + 32768 + dst0);
    STAGE(B, sB_lo[1] + koff2, LB + 32768 + dst1);
    // pre-bar read avHi(t) (cross-wave-confirmed at W0(t) bar#1)
#pragma unroll
    for (int m = 0; m < 4; ++m) {
        avHi[m][0] = *(const bf16x8*)(pA0 + LB + 16384 + m * 2048);
        avHi[m][1] = *(const bf16x8*)(pA1 + LB + 16384 + m * 2048);
    }
    asm volatile("s_waitcnt vmcnt(8)" ::: "memory");
    __builtin_amdgcn_s_barrier();
    __builtin_amdgcn_sched_barrier(0);
    __builtin_amdgcn_s_setprio(1);
    mfma_half(acc[2], avHi, bvHi);         // Q(1,1)
    mfma_half(acc[3], avHi, bvLo);         // Q(1,0)
    __builtin_amdgcn_s_setprio(0);
    __builtin_amdgcn_s_barrier();
}

__global__ __launch_bounds__(512, 2) void gemm_bf16_8phase(
    const __hip_bfloat16* __restrict__ A, const __hip_bfloat16* __restrict__ B,
    const float* __restrict__ bias, float* __restrict__ C)
{
    extern __shared__ char lds[];  // 131072 B

    const int tid = threadIdx.x;
    const int lane = tid & 63;
    const int wid = tid >> 6;       // 0..7
    const int wr = wid >> 2;        // 0..1 (M split)
    const int wc = wid & 3;         // 0..3 (N split)
    const int l15 = lane & 15;
    const int kgrp = lane >> 4;

    // XCD stripe (bijective) + 2D brick order (round-9): per-XCD 8x4 bricks.
    const int wg = blockIdx.x;
    const int s = (wg & 7) * (NWG / 8) + (wg >> 3);
    int bm, bn;
    if (s < 1280) {                 // 10 groups of width 4 (8x4 bricks)
        const int g = s >> 7;
        const int j = s & 127;
        bm = j >> 2;
        bn = g * 4 + (j & 3);
    } else {                        // last group: width 3
        const int j = s - 1280;     // 0..95
        bm = j / 3;
        bn = 40 + j % 3;
    }
    const int m0 = bm * BM;
    const int n0 = bn * BN;

    // ---- Precomputed stage-source element offsets (per lane, once) ----
    int sA_lo[2], sA_hi[2], sB_lo[2], sB_hi[2];
#pragma unroll
    for (int c = 0; c < 2; ++c) {
        const int idx = c * 512 + tid;          // 0..1023 chunk id (linear LDS)
        const int row = idx >> 3;               // 0..127
        const int scol = (idx & 7) ^ (row & 7); // pre-swizzled source chunk
        sA_lo[c] = (m0 + row) * K_DIM + scol * 8;
        sA_hi[c] = sA_lo[c] + 128 * K_DIM;
        sB_lo[c] = (n0 + row) * K_DIM + scol * 8;
        sB_hi[c] = sB_lo[c] + 128 * K_DIM;
    }
    const int dst0 = wid * 1024;          // (c*512 + wid*64)*16, c=0
    const int dst1 = 8192 + wid * 1024;   // c=1

    // ---- Precomputed fragment-read base pointers (buf0; buf1 = +65536) ----
    const int xlo = l15 & 7;
    const char* pA0 = lds + (wr * 64 + l15) * 128 + ((kgrp) ^ xlo) * 16;
    const char* pA1 = lds + (wr * 64 + l15) * 128 + ((4 + kgrp) ^ xlo) * 16;
    const char* pB0 = lds + 32768 + (wc * 32 + l15) * 128 + ((kgrp) ^ xlo) * 16;
    const char* pB1 = lds + 32768 + (wc * 32 + l15) * 128 + ((4 + kgrp) ^ xlo) * 16;

    // acc quadrants: 0=(0,0) 1=(0,1) 2=(1,1) 3=(1,0)  (mq,nq)
    f32x4 acc[4][4][2];
#pragma unroll
    for (int q = 0; q < 4; ++q)
#pragma unroll
        for (int m = 0; m < 4; ++m)
#pragma unroll
            for (int n = 0; n < 2; ++n)
                acc[q][m][n] = (f32x4){0.f, 0.f, 0.f, 0.f};

    // Prologue pair-stream (FIFO matches steady state):
    //  {Alo(0),Blo(0)} ; {Ahi(0),Bhi(0)} ; {Alo(1),Blo(1)}
    STAGE(A, sA_lo[0], dst0);                 STAGE(A, sA_lo[1], dst1);
    STAGE(B, sB_lo[0], 32768 + dst0);         STAGE(B, sB_lo[1], 32768 + dst1);
    STAGE(A, sA_hi[0], 16384 + dst0);         STAGE(A, sA_hi[1], 16384 + dst1);
    STAGE(B, sB_hi[0], 49152 + dst0);         STAGE(B, sB_hi[1], 49152 + dst1);
    STAGE(A, sA_lo[0] + 64, 65536 + dst0);    STAGE(A, sA_lo[1] + 64, 65536 + dst1);
    STAGE(B, sB_lo[0] + 64, 98304 + dst0);    STAGE(B, sB_lo[1] + 64, 98304 + dst1);
    asm volatile("s_waitcnt vmcnt(8)" ::: "memory"); // confirms {Alo,Blo}(0)
    __builtin_amdgcn_s_barrier();

    for (int t = 0; t < NT; t += 2) {
        tile_body<0>(t,     acc, A, B, lds, sA_lo, sA_hi, sB_lo, sB_hi,
                     dst0, dst1, pA0, pA1, pB0, pB1);
        tile_body<1>(t + 1, acc, A, B, lds, sA_lo, sA_hi, sB_lo, sB_hi,
                     dst0, dst1, pA0, pA1, pB0, pB1);
    }

    // Epilogue (C/D layout: col = lane&15, row = (lane>>4)*4 + reg).
    // Nontemporal: C written once, never re-read -> don't churn L3.
#pragma unroll
    for (int q = 0; q < 4; ++q) {
        const int mqe = q >> 1;
        const int nqe = (q == 1 || q == 2) ? 1 : 0;
#pragma unroll
        for (int n = 0; n < 2; ++n) {
            const int col = n0 + nqe * 128 + wc * 32 + n * 16 + l15;
            const float bval = bias[col];
#pragma unroll
            for (int m = 0; m < 4; ++m) {
                const int row = m0 + mqe * 128 + wr * 64 + m * 16 + kgrp * 4;
#pragma unroll
                for (int r = 0; r < 4; ++r)
                    __builtin_nontemporal_store(acc[q][m][n][r] + bval,
                        &C[(size_t)(row + r) * N_DIM + col]);
            }
        }
    }
}

// ---------------------------------------------------------------------------
extern "C" void kernel_launch(void* const* d_in, const int* in_sizes, int n_in,
                              void* d_out, int out_size, void* d_ws, size_t ws_size,
                              hipStream_t stream)
{
    const float* x      = (const float*)d_in[0];  // [4,2048,4096] f32
    const int*   codes  = (const int*)d_in[1];    // [704512,64] i32
    const float* absmax = (const float*)d_in[2];  // [704512] f32
    const float* bias   = (const float*)d_in[3];  // [11008] f32
    float* out = (float*)d_out;                   // [4,2048,11008] f32

    const size_t w_bytes = (size_t)N_DIM * K_DIM * sizeof(__hip_bfloat16);
    const size_t x_bytes = (size_t)M_DIM * K_DIM * sizeof(__hip_bfloat16);
    if (ws_size < w_bytes + x_bytes) {
        fprintf(stderr, "kernel_launch: ws_size=%zu < needed %zu\n",
                ws_size, w_bytes + x_bytes);
        return;
    }
    __hip_bfloat16* wbf = (__hip_bfloat16*)d_ws;
    __hip_bfloat16* xbf = (__hip_bfloat16*)((char*)d_ws + w_bytes);

    // Allow 128 KiB dynamic LDS (idempotent host-side call; capture-safe).
    hipFuncSetAttribute((const void*)gemm_bf16_8phase,
                        hipFuncAttributeMaxDynamicSharedMemorySize, 131072);

    prep_kernel<<<dim3(DEQ_BLOCKS + CVT_BLOCKS), dim3(256), 0, stream>>>(
        codes, absmax, x, wbf, xbf);
    gemm_bf16_8phase<<<dim3(NWG), dim3(512), 131072, stream>>>(xbf, wbf, bias, out);
}